// Round 1
// baseline (732.463 us; speedup 1.0000x reference)
//
#include <hip/hip_runtime.h>
#include <hip/hip_bf16.h>
#include <math.h>

#define HIDDEN 2048
#define NHEADS 16
#define NKV 4
#define HD 128
#define SEQ 2048
#define BATCH 2
#define MTOT (BATCH*SEQ)     // 4096
#define NQ (NHEADS*HD)       // 2048
#define NKVD (NKV*HD)        // 512

typedef __attribute__((ext_vector_type(8))) short short8;
typedef __attribute__((ext_vector_type(4))) float float4v;

static __device__ __forceinline__ unsigned short f2bf(float f) {
  union { float f; unsigned int u; } v; v.f = f;
  unsigned int r = v.u + 0x7FFF + ((v.u >> 16) & 1);
  return (unsigned short)(r >> 16);
}
static __device__ __forceinline__ float bf2f(unsigned short h) {
  union { unsigned int u; float f; } v; v.u = ((unsigned int)h) << 16;
  return v.f;
}

// ---------------- cast fp32 -> bf16 (vectorized x4) ----------------
__global__ void cast_f32_bf16(const float* __restrict__ in,
                              unsigned short* __restrict__ out, int n) {
  int i = (blockIdx.x * blockDim.x + threadIdx.x) * 4;
  if (i < n) {
    float4 v = *(const float4*)(in + i);
    ushort4 o;
    o.x = f2bf(v.x); o.y = f2bf(v.y); o.z = f2bf(v.z); o.w = f2bf(v.w);
    *(ushort4*)(out + i) = o;
  }
}

// ---------------- transpose + cast: W[K][N] fp32 -> Wt[N][K] bf16 ----------------
__global__ void transpose_cast(const float* __restrict__ W,
                               unsigned short* __restrict__ Wt, int K, int N) {
  __shared__ float tile[32][33];
  int tn = blockIdx.x * 32;
  int tk = blockIdx.y * 32;
  int tx = threadIdx.x & 31;
  int ty = threadIdx.x >> 5;  // 0..7
  #pragma unroll
  for (int i = 0; i < 4; i++) {
    int k = tk + ty + i * 8;
    tile[ty + i * 8][tx] = W[(size_t)k * N + tn + tx];
  }
  __syncthreads();
  #pragma unroll
  for (int i = 0; i < 4; i++) {
    int n = tn + ty + i * 8;
    Wt[(size_t)n * K + tk + tx] = f2bf(tile[tx][ty + i * 8]);
  }
}

// ---------------- RoPE in place on [B][S][nheads][128] bf16 ----------------
__global__ void rope_kernel(unsigned short* __restrict__ Qb, int nheads) {
  int idx = blockIdx.x * blockDim.x + threadIdx.x;
  int d = idx & 63;
  int hr = idx >> 6;                 // (b*SEQ + s)*nheads + h
  int spos = (hr / nheads) % SEQ;
  size_t base = (size_t)hr * HD;
  float inv = 1.0f / powf(10000.0f, (float)d / 64.0f);
  float ang = (float)spos * inv;
  float sn, cs;
  sincosf(ang, &sn, &cs);
  float q1 = bf2f(Qb[base + d]);
  float q2 = bf2f(Qb[base + d + 64]);
  Qb[base + d]      = f2bf(q1 * cs - q2 * sn);
  Qb[base + d + 64] = f2bf(q2 * cs + q1 * sn);
}

// ---------------- GEMM: A[M][K] bf16 x Bt[N][K] bf16 -> C[M][N] (OutT) ----------------
// 128x128 block tile, BK=32, 4 waves (2x2) of 64x64, mfma 16x16x32 bf16.
template <typename OutT>
__global__ __launch_bounds__(256) void gemm_bt(
    const unsigned short* __restrict__ A,
    const unsigned short* __restrict__ Bt,
    OutT* __restrict__ C, int M, int N, int K) {
  constexpr int LDT = 40;  // 32 + 8 pad (80B rows: 2-way bank alias = free)
  __shared__ unsigned short As[128 * LDT];
  __shared__ unsigned short Bs[128 * LDT];
  int bm = blockIdx.y * 128;
  int bn = blockIdx.x * 128;
  int tid = threadIdx.x;
  int w = tid >> 6;
  int lane = tid & 63;
  int wm = (w >> 1) * 64;
  int wn = (w & 1) * 64;
  int m16 = lane & 15;
  int quad = lane >> 4;
  int r0 = tid >> 2, c0 = tid & 3;

  float4v acc[4][4];
  #pragma unroll
  for (int i = 0; i < 4; i++)
    #pragma unroll
    for (int j = 0; j < 4; j++) acc[i][j] = (float4v)0.0f;

  for (int k0 = 0; k0 < K; k0 += 32) {
    #pragma unroll
    for (int s = 0; s < 2; s++) {
      int row = r0 + s * 64;
      short8 av = *(const short8*)(A + (size_t)(bm + row) * K + k0 + c0 * 8);
      *(short8*)(&As[row * LDT + c0 * 8]) = av;
      short8 bv = *(const short8*)(Bt + (size_t)(bn + row) * K + k0 + c0 * 8);
      *(short8*)(&Bs[row * LDT + c0 * 8]) = bv;
    }
    __syncthreads();
    short8 af[4], bfr[4];
    #pragma unroll
    for (int i = 0; i < 4; i++)
      af[i] = *(const short8*)(&As[(wm + i * 16 + m16) * LDT + quad * 8]);
    #pragma unroll
    for (int j = 0; j < 4; j++)
      bfr[j] = *(const short8*)(&Bs[(wn + j * 16 + m16) * LDT + quad * 8]);
    #pragma unroll
    for (int i = 0; i < 4; i++)
      #pragma unroll
      for (int j = 0; j < 4; j++)
        acc[i][j] = __builtin_amdgcn_mfma_f32_16x16x32_bf16(af[i], bfr[j], acc[i][j], 0, 0, 0);
    __syncthreads();
  }

  #pragma unroll
  for (int i = 0; i < 4; i++)
    #pragma unroll
    for (int j = 0; j < 4; j++)
      #pragma unroll
      for (int r = 0; r < 4; r++) {
        int row = bm + wm + i * 16 + quad * 4 + r;
        int col = bn + wn + j * 16 + m16;
        float v = acc[i][j][r];
        if constexpr (sizeof(OutT) == 2)
          ((unsigned short*)C)[(size_t)row * N + col] = f2bf(v);
        else
          ((float*)C)[(size_t)row * N + col] = v;
      }
}

// ---------------- Flash attention (causal, GQA) ----------------
// Q [B][S][16][128], K/V [B][S][4][128] bf16 -> O [B][S][16][128] bf16
// block = 64 q rows (4 waves x 16), k-tiles of 64.
__global__ __launch_bounds__(256) void flash_attn(
    const unsigned short* __restrict__ Q,
    const unsigned short* __restrict__ K,
    const unsigned short* __restrict__ V,
    unsigned short* __restrict__ O) {
  constexpr int LDK = 136;  // 128 + 8 pad
  constexpr int LDV = 72;   // 64 + 8 pad
  constexpr int LDP = 72;
  __shared__ unsigned short Ks[64 * LDK];
  __shared__ unsigned short Vs[128 * LDV];   // V transposed: [d][k]
  __shared__ unsigned short Ps[4 * 16 * LDP];

  int qt = (gridDim.x - 1) - blockIdx.x;  // heavy tiles first
  int h = blockIdx.y;
  int b = blockIdx.z;
  int kvh = h >> 2;
  int tid = threadIdx.x;
  int w = tid >> 6, lane = tid & 63;
  int m16 = lane & 15, quad = lane >> 4;

  // Q fragments (A-operand layout): rows w*16 + m16, k = c*32 + quad*8 + j
  int qrow = qt * 64 + w * 16 + m16;
  const size_t qbase = (((size_t)b * SEQ + qrow) * NHEADS + h) * HD;
  short8 qf[4];
  #pragma unroll
  for (int c = 0; c < 4; c++)
    qf[c] = *(const short8*)(Q + qbase + c * 32 + quad * 8);

  float4v oacc[8];
  #pragma unroll
  for (int i = 0; i < 8; i++) oacc[i] = (float4v)0.0f;
  float mi[4], li[4];
  #pragma unroll
  for (int r = 0; r < 4; r++) { mi[r] = -1e30f; li[r] = 0.0f; }

  const float scale = 0.08838834764831845f;  // 1/sqrt(128)

  for (int kt = 0; kt <= qt; kt++) {
    // stage K rows + V transposed
    #pragma unroll
    for (int s = 0; s < 4; s++) {
      int cidx = tid + s * 256;
      int row = cidx >> 4;   // 0..63
      int c8 = cidx & 15;    // 0..15
      size_t gb = (((size_t)b * SEQ + kt * 64 + row) * NKV + kvh) * HD + c8 * 8;
      short8 kv = *(const short8*)(K + gb);
      *(short8*)(&Ks[row * LDK + c8 * 8]) = kv;
      short8 vv = *(const short8*)(V + gb);
      #pragma unroll
      for (int jj = 0; jj < 8; jj++)
        Vs[(c8 * 8 + jj) * LDV + row] = (unsigned short)vv[jj];
    }
    __syncthreads();

    // scores: 4 subtiles of 16 k-cols
    float sv[4][4];
    #pragma unroll
    for (int s4 = 0; s4 < 4; s4++) {
      bool active_tile = (kt * 64 + s4 * 16) <= (qt * 64 + w * 16 + 15);
      if (active_tile) {
        float4v sacc = (float4v)0.0f;
        #pragma unroll
        for (int c = 0; c < 4; c++) {
          short8 kf = *(const short8*)(&Ks[(s4 * 16 + m16) * LDK + c * 32 + quad * 8]);
          sacc = __builtin_amdgcn_mfma_f32_16x16x32_bf16(qf[c], kf, sacc, 0, 0, 0);
        }
        int kcol = kt * 64 + s4 * 16 + m16;
        #pragma unroll
        for (int r = 0; r < 4; r++) {
          int qr = qt * 64 + w * 16 + quad * 4 + r;
          float t = sacc[r] * scale;
          sv[s4][r] = (kcol > qr) ? -1e30f : t;
        }
      } else {
        #pragma unroll
        for (int r = 0; r < 4; r++) sv[s4][r] = -1e30f;
      }
    }

    // online softmax per row (row lives in 16 lanes of this quad group)
    #pragma unroll
    for (int r = 0; r < 4; r++) {
      float mloc = fmaxf(fmaxf(sv[0][r], sv[1][r]), fmaxf(sv[2][r], sv[3][r]));
      mloc = fmaxf(mloc, __shfl_xor(mloc, 1, 64));
      mloc = fmaxf(mloc, __shfl_xor(mloc, 2, 64));
      mloc = fmaxf(mloc, __shfl_xor(mloc, 4, 64));
      mloc = fmaxf(mloc, __shfl_xor(mloc, 8, 64));
      float mnew = fmaxf(mi[r], mloc);
      float msafe = (mnew <= -1e29f) ? 0.0f : mnew;
      float pr[4]; float rs = 0.0f;
      #pragma unroll
      for (int s4 = 0; s4 < 4; s4++) {
        float p = __expf(sv[s4][r] - msafe);
        pr[s4] = p; rs += p;
      }
      rs += __shfl_xor(rs, 1, 64);
      rs += __shfl_xor(rs, 2, 64);
      rs += __shfl_xor(rs, 4, 64);
      rs += __shfl_xor(rs, 8, 64);
      float alpha = __expf(mi[r] - msafe);   // mi=-1e30 -> 0 (li,oacc are 0 then)
      li[r] = li[r] * alpha + rs;
      mi[r] = mnew;
      #pragma unroll
      for (int ds = 0; ds < 8; ds++) oacc[ds][r] *= alpha;
      #pragma unroll
      for (int s4 = 0; s4 < 4; s4++)
        Ps[(w * 16 + quad * 4 + r) * LDP + s4 * 16 + m16] = f2bf(pr[s4]);
    }

    // PV: P(16x64) x V(64x128); P from LDS in A-layout, V^T gives contiguous B-frags
    short8 pf[2];
    #pragma unroll
    for (int kc = 0; kc < 2; kc++)
      pf[kc] = *(const short8*)(&Ps[(w * 16 + m16) * LDP + kc * 32 + quad * 8]);
    #pragma unroll
    for (int ds = 0; ds < 8; ds++)
      #pragma unroll
      for (int kc = 0; kc < 2; kc++) {
        short8 vf = *(const short8*)(&Vs[(ds * 16 + m16) * LDV + kc * 32 + quad * 8]);
        oacc[ds] = __builtin_amdgcn_mfma_f32_16x16x32_bf16(pf[kc], vf, oacc[ds], 0, 0, 0);
      }
    __syncthreads();
  }

  // epilogue: O = oacc / l
  #pragma unroll
  for (int ds = 0; ds < 8; ds++)
    #pragma unroll
    for (int r = 0; r < 4; r++) {
      int qr = qt * 64 + w * 16 + quad * 4 + r;
      float v = oacc[ds][r] / li[r];
      O[(((size_t)b * SEQ + qr) * NHEADS + h) * HD + ds * 16 + m16] = f2bf(v);
    }
}

extern "C" void kernel_launch(void* const* d_in, const int* in_sizes, int n_in,
                              void* d_out, int out_size, void* d_ws, size_t ws_size,
                              hipStream_t stream) {
  const float* x  = (const float*)d_in[0];
  const float* Wq = (const float*)d_in[1];
  const float* Wk = (const float*)d_in[2];
  const float* Wv = (const float*)d_in[3];
  const float* Wo = (const float*)d_in[4];
  float* out = (float*)d_out;

  unsigned short* ws = (unsigned short*)d_ws;
  unsigned short* xb  = ws;                       // 4096*2048
  unsigned short* Wqt = xb  + (size_t)MTOT * HIDDEN;
  unsigned short* Wkt = Wqt + (size_t)NQ * HIDDEN;
  unsigned short* Wvt = Wkt + (size_t)NKVD * HIDDEN;
  unsigned short* Wot = Wvt + (size_t)NKVD * HIDDEN;
  unsigned short* Qb  = Wot + (size_t)NQ * HIDDEN;       // post-GEMM Q (bf16)
  unsigned short* Kb  = Qb  + (size_t)MTOT * NQ;
  unsigned short* Vb  = Kb  + (size_t)MTOT * NKVD;
  unsigned short* Ab  = Vb  + (size_t)MTOT * NKVD;       // attention output

  // 1. cast x
  cast_f32_bf16<<<(MTOT * HIDDEN / 4 + 255) / 256, 256, 0, stream>>>(x, xb, MTOT * HIDDEN);
  // 2. transpose weights -> [N][K] bf16
  transpose_cast<<<dim3(NQ / 32, HIDDEN / 32), 256, 0, stream>>>(Wq, Wqt, HIDDEN, NQ);
  transpose_cast<<<dim3(NKVD / 32, HIDDEN / 32), 256, 0, stream>>>(Wk, Wkt, HIDDEN, NKVD);
  transpose_cast<<<dim3(NKVD / 32, HIDDEN / 32), 256, 0, stream>>>(Wv, Wvt, HIDDEN, NKVD);
  transpose_cast<<<dim3(NQ / 32, HIDDEN / 32), 256, 0, stream>>>(Wo, Wot, NQ, HIDDEN);
  // 3. QKV projections
  gemm_bt<unsigned short><<<dim3(NQ / 128, MTOT / 128), 256, 0, stream>>>(xb, Wqt, Qb, MTOT, NQ, HIDDEN);
  gemm_bt<unsigned short><<<dim3(NKVD / 128, MTOT / 128), 256, 0, stream>>>(xb, Wkt, Kb, MTOT, NKVD, HIDDEN);
  gemm_bt<unsigned short><<<dim3(NKVD / 128, MTOT / 128), 256, 0, stream>>>(xb, Wvt, Vb, MTOT, NKVD, HIDDEN);
  // 4. RoPE on Q and K
  rope_kernel<<<(BATCH * SEQ * NHEADS * 64) / 256, 256, 0, stream>>>(Qb, NHEADS);
  rope_kernel<<<(BATCH * SEQ * NKV * 64) / 256, 256, 0, stream>>>(Kb, NKV);
  // 5. flash attention
  flash_attn<<<dim3(SEQ / 64, NHEADS, BATCH), 256, 0, stream>>>(Qb, Kb, Vb, Ab);
  // 6. output projection -> fp32 d_out
  gemm_bt<float><<<dim3(HIDDEN / 128, MTOT / 128), 256, 0, stream>>>(Ab, Wot, out, MTOT, HIDDEN, NQ);
}

// Round 2
// 434.646 us; speedup vs baseline: 1.6852x; 1.6852x over previous
//
#include <hip/hip_runtime.h>
#include <hip/hip_bf16.h>
#include <math.h>

#define HIDDEN 2048
#define NHEADS 16
#define NKV 4
#define HD 128
#define SEQ 2048
#define BATCH 2
#define MTOT (BATCH*SEQ)     // 4096
#define NQ (NHEADS*HD)       // 2048
#define NKVD (NKV*HD)        // 512

typedef __attribute__((ext_vector_type(8))) short short8;
typedef __attribute__((ext_vector_type(4))) float float4v;

static __device__ __forceinline__ unsigned short f2bf(float f) {
  union { float f; unsigned int u; } v; v.f = f;
  unsigned int r = v.u + 0x7FFF + ((v.u >> 16) & 1);
  return (unsigned short)(r >> 16);
}
static __device__ __forceinline__ float bf2f(unsigned short h) {
  union { unsigned int u; float f; } v; v.u = ((unsigned int)h) << 16;
  return v.f;
}

// async global->LDS, 16B per lane; LDS dest = uniform base + lane*16
static __device__ __forceinline__ void async16(const unsigned short* g, unsigned short* l) {
  __builtin_amdgcn_global_load_lds(
      (const __attribute__((address_space(1))) unsigned int*)g,
      (__attribute__((address_space(3))) unsigned int*)l, 16, 0, 0);
}

// ---------------- cast fp32 -> bf16 (vectorized x4) ----------------
__global__ void cast_f32_bf16(const float* __restrict__ in,
                              unsigned short* __restrict__ out, int n) {
  int i = (blockIdx.x * blockDim.x + threadIdx.x) * 4;
  if (i < n) {
    float4 v = *(const float4*)(in + i);
    ushort4 o;
    o.x = f2bf(v.x); o.y = f2bf(v.y); o.z = f2bf(v.z); o.w = f2bf(v.w);
    *(ushort4*)(out + i) = o;
  }
}

// ---------------- transpose + cast: W[K][N] fp32 -> Wt[N][K] bf16 ----------------
__global__ void transpose_cast(const float* __restrict__ W,
                               unsigned short* __restrict__ Wt, int K, int N) {
  __shared__ float tile[32][33];
  int tn = blockIdx.x * 32;
  int tk = blockIdx.y * 32;
  int tx = threadIdx.x & 31;
  int ty = threadIdx.x >> 5;  // 0..7
  #pragma unroll
  for (int i = 0; i < 4; i++) {
    int k = tk + ty + i * 8;
    tile[ty + i * 8][tx] = W[(size_t)k * N + tn + tx];
  }
  __syncthreads();
  #pragma unroll
  for (int i = 0; i < 4; i++) {
    int n = tn + ty + i * 8;
    Wt[(size_t)n * K + tk + tx] = f2bf(tile[tx][ty + i * 8]);
  }
}

// ---------------- RoPE in place on [B][S][nheads][128] bf16 ----------------
__global__ void rope_kernel(unsigned short* __restrict__ Qb, int nheads) {
  int idx = blockIdx.x * blockDim.x + threadIdx.x;
  int d = idx & 63;
  int hr = idx >> 6;                 // (b*SEQ + s)*nheads + h
  int spos = (hr / nheads) % SEQ;
  size_t base = (size_t)hr * HD;
  float inv = exp2f((float)d * -0.2076205059304601f);  // 10000^(-d/64)
  float ang = (float)spos * inv;
  float sn, cs;
  sincosf(ang, &sn, &cs);
  float q1 = bf2f(Qb[base + d]);
  float q2 = bf2f(Qb[base + d + 64]);
  Qb[base + d]      = f2bf(q1 * cs - q2 * sn);
  Qb[base + d + 64] = f2bf(q2 * cs + q1 * sn);
}

// ---------------- GEMM: A[M][K] x Bt[N][K] bf16 -> C[M][N], async LDS staging ----------------
// 128x128 tile, BK=32, 4 waves (2x2) of 64x64, mfma 16x16x32 bf16, unpadded LDS.
template <typename OutT>
__global__ __launch_bounds__(256) void gemm_bt_async(
    const unsigned short* __restrict__ A,
    const unsigned short* __restrict__ Bt,
    OutT* __restrict__ C, int M, int N, int K) {
  __shared__ unsigned short As[128 * 32];
  __shared__ unsigned short Bs[128 * 32];
  int bm = blockIdx.y * 128;
  int bn = blockIdx.x * 128;
  int tid = threadIdx.x;
  int w = tid >> 6, lane = tid & 63;
  int wm = (w >> 1) * 64, wn = (w & 1) * 64;
  int m16 = lane & 15, quad = lane >> 4;
  int lrow = lane >> 2, lch = lane & 3;   // staging: 16 rows x 4 chunks per inst

  float4v acc[4][4];
  #pragma unroll
  for (int i = 0; i < 4; i++)
    #pragma unroll
    for (int j = 0; j < 4; j++) acc[i][j] = (float4v)0.0f;

  const unsigned short* Ag = A + (size_t)(bm + w * 32 + lrow) * K + lch * 8;
  const unsigned short* Bg = Bt + (size_t)(bn + w * 32 + lrow) * K + lch * 8;
  unsigned short* Asl = As + w * 1024;   // (w*32 rows)*32
  unsigned short* Bsl = Bs + w * 1024;

  for (int k0 = 0; k0 < K; k0 += 32) {
    __syncthreads();
    #pragma unroll
    for (int i = 0; i < 2; i++) {
      async16(Ag + (size_t)i * 16 * K + k0, Asl + i * 512);
      async16(Bg + (size_t)i * 16 * K + k0, Bsl + i * 512);
    }
    __syncthreads();
    short8 af[4], bfr[4];
    #pragma unroll
    for (int i = 0; i < 4; i++)
      af[i] = *(const short8*)(&As[(wm + i * 16 + m16) * 32 + quad * 8]);
    #pragma unroll
    for (int j = 0; j < 4; j++)
      bfr[j] = *(const short8*)(&Bs[(wn + j * 16 + m16) * 32 + quad * 8]);
    #pragma unroll
    for (int i = 0; i < 4; i++)
      #pragma unroll
      for (int j = 0; j < 4; j++)
        acc[i][j] = __builtin_amdgcn_mfma_f32_16x16x32_bf16(af[i], bfr[j], acc[i][j], 0, 0, 0);
  }

  #pragma unroll
  for (int i = 0; i < 4; i++)
    #pragma unroll
    for (int j = 0; j < 4; j++)
      #pragma unroll
      for (int r = 0; r < 4; r++) {
        int row = bm + wm + i * 16 + quad * 4 + r;
        int col = bn + wn + j * 16 + m16;
        float v = acc[i][j][r];
        if constexpr (sizeof(OutT) == 2)
          ((unsigned short*)C)[(size_t)row * N + col] = f2bf(v);
        else
          ((float*)C)[(size_t)row * N + col] = v;
      }
}

// ---------------- Flash attention (causal, GQA), S^T formulation ----------------
// Q [B][S][16][128] bf16 (roped), K [B][S][4][128] bf16 (roped),
// Vt [512][MTOT] bf16 (V^T: feature-major) -> O [B][S][16][128] bf16.
// Block: 256 thr = 4 waves; waves 0-1 -> q-tile H=31-bx, waves 2-3 -> q-tile L=bx.
// Each wave: 32 q rows (2 x 16-subtiles). K-tile = 64 keys.
__global__ __launch_bounds__(256, 2) void flash_attn(
    const unsigned short* __restrict__ Q,
    const unsigned short* __restrict__ K,
    const unsigned short* __restrict__ Vt,
    unsigned short* __restrict__ O) {
  // chunk-major unpadded layouts (async-staged, conflict-free b128 reads):
  __shared__ unsigned short Ks[4 * 64 * 32];   // [dchunk c][key row][32 d]
  __shared__ unsigned short Vs[2 * 128 * 32];  // [kchunk kc][d row][32 seq]
  __shared__ unsigned int   Ps[128 * 36];      // P[q local][k/2] packed bf16x2

  int bx = blockIdx.x;            // 0..15
  int h  = blockIdx.y;
  int b  = blockIdx.z;
  int kvh = h >> 2;
  int H = 31 - bx, L = bx;        // q-tile indices (64 rows each)
  int tid = threadIdx.x;
  int w = tid >> 6, lane = tid & 63;
  int m16 = lane & 15, quad = lane >> 4;
  int lrow = lane >> 2, lch = lane & 3;

  int wqbase = (w < 2) ? (H * 64 + w * 32) : (L * 64 + (w - 2) * 32);
  int wqmax = wqbase + 31;
  int qlocal0 = w * 32;           // LDS-P row base for this wave

  // Q fragments (B-operand): n=q=m16, k = c*32 + quad*8 + j, per q-subtile
  short8 qf[2][4];
  #pragma unroll
  for (int qs = 0; qs < 2; qs++) {
    size_t qbase = (((size_t)b * SEQ + wqbase + qs * 16 + m16) * NHEADS + h) * HD;
    #pragma unroll
    for (int c = 0; c < 4; c++)
      qf[qs][c] = *(const short8*)(Q + qbase + c * 32 + quad * 8);
  }

  float4v oacc[8][2];
  #pragma unroll
  for (int ds = 0; ds < 8; ds++) { oacc[ds][0] = (float4v)0.0f; oacc[ds][1] = (float4v)0.0f; }
  float mi[2] = {-1e30f, -1e30f}, li[2] = {0.0f, 0.0f};
  const float scale = 0.08838834764831845f;  // 1/sqrt(128)

  for (int kt = 0; kt <= H; kt++) {
    int ktb = kt * 64;
    __syncthreads();   // prior-iteration LDS reads done
    // stage K tile: wave w -> d-chunk c=w, 4 insts of 16 key-rows
    {
      const unsigned short* Kg = K + (((size_t)b * SEQ + ktb + lrow) * NKV + kvh) * HD
                                   + w * 32 + lch * 8;
      unsigned short* Kl = Ks + w * 2048;
      #pragma unroll
      for (int i = 0; i < 4; i++)
        async16(Kg + (size_t)i * 16 * NKV * HD, Kl + i * 512);
    }
    // stage V^T tile: wave w -> (kc = w>>1, 4 insts of 16 d-rows)
    {
      int kc = w >> 1, ip = (w & 1) * 4;
      const unsigned short* Vg = Vt + ((size_t)kvh * HD + ip * 16 + lrow) * MTOT
                                    + (size_t)b * SEQ + ktb + kc * 32 + lch * 8;
      unsigned short* Vl = Vs + kc * 4096 + ip * 512;
      #pragma unroll
      for (int i = 0; i < 4; i++)
        async16(Vg + (size_t)i * 16 * MTOT, Vl + i * 512);
    }
    __syncthreads();   // staging visible

    if (ktb <= wqmax) {
      // ---- S^T = K x Q^T : D[kcol][q], A = K-frag, B = Q-frag ----
      float4v sacc[2][4];
      #pragma unroll
      for (int qs = 0; qs < 2; qs++)
        #pragma unroll
        for (int s4 = 0; s4 < 4; s4++) sacc[qs][s4] = (float4v)0.0f;
      #pragma unroll
      for (int s4 = 0; s4 < 4; s4++)
        #pragma unroll
        for (int c = 0; c < 4; c++) {
          short8 kf = *(const short8*)(&Ks[c * 2048 + (s4 * 16 + m16) * 32 + quad * 8]);
          sacc[0][s4] = __builtin_amdgcn_mfma_f32_16x16x32_bf16(kf, qf[0][c], sacc[0][s4], 0, 0, 0);
          sacc[1][s4] = __builtin_amdgcn_mfma_f32_16x16x32_bf16(kf, qf[1][c], sacc[1][s4], 0, 0, 0);
        }

      // ---- online softmax per q-subtile; lane owns one q-row (col=q=m16) ----
      #pragma unroll
      for (int qs = 0; qs < 2; qs++) {
        int qabs = wqbase + qs * 16 + m16;
        float sv[4][4];
        float mloc = -1e30f;
        #pragma unroll
        for (int s4 = 0; s4 < 4; s4++)
          #pragma unroll
          for (int r = 0; r < 4; r++) {
            int kabs = ktb + s4 * 16 + quad * 4 + r;
            float t = sacc[qs][s4][r] * scale;
            sv[s4][r] = (kabs > qabs) ? -1e30f : t;
            mloc = fmaxf(mloc, sv[s4][r]);
          }
        mloc = fmaxf(mloc, __shfl_xor(mloc, 16, 64));
        mloc = fmaxf(mloc, __shfl_xor(mloc, 32, 64));
        float mnew = fmaxf(mi[qs], mloc);
        float p[4][4];
        float rs = 0.0f;
        #pragma unroll
        for (int s4 = 0; s4 < 4; s4++)
          #pragma unroll
          for (int r = 0; r < 4; r++) {
            p[s4][r] = __expf(sv[s4][r] - mnew);
            rs += p[s4][r];
          }
        rs += __shfl_xor(rs, 16, 64);
        rs += __shfl_xor(rs, 32, 64);
        float alpha = __expf(mi[qs] - mnew);
        li[qs] = li[qs] * alpha + rs;
        mi[qs] = mnew;
        #pragma unroll
        for (int ds = 0; ds < 8; ds++) oacc[ds][qs] *= alpha;
        // pack P -> LDS as P[q][k/2] (u32 = bf16 pair), wave-private, b64 writes
        int prow = (qlocal0 + qs * 16 + m16) * 36;
        #pragma unroll
        for (int s4 = 0; s4 < 4; s4++) {
          uint2 u;
          u.x = ((unsigned)f2bf(p[s4][1]) << 16) | f2bf(p[s4][0]);
          u.y = ((unsigned)f2bf(p[s4][3]) << 16) | f2bf(p[s4][2]);
          *(uint2*)(&Ps[prow + s4 * 8 + quad * 2]) = u;
        }
      }

      // ---- O^T += V^T x P^T : D[d][q], A = V-frag, B = P-frag ----
      #pragma unroll
      for (int kc = 0; kc < 2; kc++) {
        short8 pf0 = *(const short8*)(&Ps[(qlocal0 + m16) * 36 + kc * 16 + quad * 4]);
        short8 pf1 = *(const short8*)(&Ps[(qlocal0 + 16 + m16) * 36 + kc * 16 + quad * 4]);
        #pragma unroll
        for (int ds = 0; ds < 8; ds++) {
          short8 vf = *(const short8*)(&Vs[kc * 4096 + (ds * 16 + m16) * 32 + quad * 8]);
          oacc[ds][0] = __builtin_amdgcn_mfma_f32_16x16x32_bf16(vf, pf0, oacc[ds][0], 0, 0, 0);
          oacc[ds][1] = __builtin_amdgcn_mfma_f32_16x16x32_bf16(vf, pf1, oacc[ds][1], 0, 0, 0);
        }
      }
    }
  }

  // ---- epilogue: O[q][d] = oacc^T / l ; pack 4 bf16 -> 8B stores ----
  #pragma unroll
  for (int qs = 0; qs < 2; qs++) {
    float inv = 1.0f / li[qs];
    int qabs = wqbase + qs * 16 + m16;
    size_t obase = (((size_t)b * SEQ + qabs) * NHEADS + h) * HD + quad * 4;
    #pragma unroll
    for (int ds = 0; ds < 8; ds++) {
      float v0 = oacc[ds][qs][0] * inv;
      float v1 = oacc[ds][qs][1] * inv;
      float v2 = oacc[ds][qs][2] * inv;
      float v3 = oacc[ds][qs][3] * inv;
      uint2 u;
      u.x = ((unsigned)f2bf(v1) << 16) | f2bf(v0);
      u.y = ((unsigned)f2bf(v3) << 16) | f2bf(v2);
      *(uint2*)(O + obase + ds * 16) = u;
    }
  }
}

extern "C" void kernel_launch(void* const* d_in, const int* in_sizes, int n_in,
                              void* d_out, int out_size, void* d_ws, size_t ws_size,
                              hipStream_t stream) {
  const float* x  = (const float*)d_in[0];
  const float* Wq = (const float*)d_in[1];
  const float* Wk = (const float*)d_in[2];
  const float* Wv = (const float*)d_in[3];
  const float* Wo = (const float*)d_in[4];
  float* out = (float*)d_out;

  unsigned short* ws = (unsigned short*)d_ws;
  unsigned short* xb  = ws;                              // [4096][2048]
  unsigned short* Wqt = xb  + (size_t)MTOT * HIDDEN;     // [2048][2048]
  unsigned short* Wkt = Wqt + (size_t)NQ * HIDDEN;       // [512][2048]
  unsigned short* Wvt = Wkt + (size_t)NKVD * HIDDEN;     // [512][2048]
  unsigned short* Wot = Wvt + (size_t)NKVD * HIDDEN;     // [2048][2048]
  unsigned short* Qb  = Wot + (size_t)NQ * HIDDEN;       // [4096][2048]
  unsigned short* Kb  = Qb  + (size_t)MTOT * NQ;         // [4096][512]
  unsigned short* Vtb = Kb  + (size_t)MTOT * NKVD;       // [512][4096]  (V^T)
  unsigned short* Ab  = Vtb + (size_t)MTOT * NKVD;       // [4096][2048]

  // 1. cast x -> bf16
  cast_f32_bf16<<<(MTOT * HIDDEN / 4 + 255) / 256, 256, 0, stream>>>(x, xb, MTOT * HIDDEN);
  // 2. transpose weights -> [N][K] bf16
  transpose_cast<<<dim3(NQ / 32, HIDDEN / 32), 256, 0, stream>>>(Wq, Wqt, HIDDEN, NQ);
  transpose_cast<<<dim3(NKVD / 32, HIDDEN / 32), 256, 0, stream>>>(Wk, Wkt, HIDDEN, NKVD);
  transpose_cast<<<dim3(NKVD / 32, HIDDEN / 32), 256, 0, stream>>>(Wv, Wvt, HIDDEN, NKVD);
  transpose_cast<<<dim3(NQ / 32, HIDDEN / 32), 256, 0, stream>>>(Wo, Wot, NQ, HIDDEN);
  // 3. projections: Q, K row-major; V produced transposed (swap operands)
  gemm_bt_async<unsigned short><<<dim3(NQ / 128, MTOT / 128), 256, 0, stream>>>(xb, Wqt, Qb, MTOT, NQ, HIDDEN);
  gemm_bt_async<unsigned short><<<dim3(NKVD / 128, MTOT / 128), 256, 0, stream>>>(xb, Wkt, Kb, MTOT, NKVD, HIDDEN);
  gemm_bt_async<unsigned short><<<dim3(MTOT / 128, NKVD / 128), 256, 0, stream>>>(Wvt, xb, Vtb, NKVD, MTOT, HIDDEN);
  // 4. RoPE on Q and K
  rope_kernel<<<(BATCH * SEQ * NHEADS * 64) / 256, 256, 0, stream>>>(Qb, NHEADS);
  rope_kernel<<<(BATCH * SEQ * NKV * 64) / 256, 256, 0, stream>>>(Kb, NKV);
  // 5. flash attention (balanced H/L q-tile pairs)
  flash_attn<<<dim3(16, NHEADS, BATCH), 256, 0, stream>>>(Qb, Kb, Vtb, Ab);
  // 6. output projection -> fp32 d_out
  gemm_bt_async<float><<<dim3(HIDDEN / 128, MTOT / 128), 256, 0, stream>>>(Ab, Wot, out, MTOT, HIDDEN, NQ);
}

// Round 4
// 327.950 us; speedup vs baseline: 2.2335x; 1.3253x over previous
//
#include <hip/hip_runtime.h>
#include <hip/hip_bf16.h>
#include <math.h>

#define HIDDEN 2048
#define NHEADS 16
#define NKV 4
#define HD 128
#define SEQ 2048
#define BATCH 2
#define MTOT (BATCH*SEQ)     // 4096
#define NQ (NHEADS*HD)       // 2048
#define NKVD (NKV*HD)        // 512
#define NQKV (NQ + 2*NKVD)   // 3072

typedef __attribute__((ext_vector_type(8))) short short8;
typedef __attribute__((ext_vector_type(4))) float float4v;

#if __has_builtin(__builtin_amdgcn_exp2f)
#define EXP2F __builtin_amdgcn_exp2f
#else
#define EXP2F exp2f
#endif
#define C1 0.1275174f   // (1/sqrt(128)) * log2(e)

static __device__ __forceinline__ unsigned short f2bf(float f) {
  union { float f; unsigned int u; } v; v.f = f;
  unsigned int r = v.u + 0x7FFF + ((v.u >> 16) & 1);
  return (unsigned short)(r >> 16);
}
static __device__ __forceinline__ float bf2f(unsigned short h) {
  union { unsigned int u; float f; } v; v.u = ((unsigned int)h) << 16;
  return v.f;
}

// async global->LDS, 16B per lane; LDS dest = uniform base + lane*16
static __device__ __forceinline__ void async16(const unsigned short* g, unsigned short* l) {
  __builtin_amdgcn_global_load_lds(
      (const __attribute__((address_space(1))) unsigned int*)g,
      (__attribute__((address_space(3))) unsigned int*)l, 16, 0, 0);
}

// ---------------- cast fp32 -> bf16 (vectorized x4) ----------------
__global__ void cast_f32_bf16(const float* __restrict__ in,
                              unsigned short* __restrict__ out, int n) {
  int i = (blockIdx.x * blockDim.x + threadIdx.x) * 4;
  if (i < n) {
    float4 v = *(const float4*)(in + i);
    ushort4 o;
    o.x = f2bf(v.x); o.y = f2bf(v.y); o.z = f2bf(v.z); o.w = f2bf(v.w);
    *(ushort4*)(out + i) = o;
  }
}

// ---------------- transpose + cast: W[K][N] fp32 -> Wt[N][K] bf16 ----------------
__global__ void transpose_cast(const float* __restrict__ W,
                               unsigned short* __restrict__ Wt, int K, int N) {
  __shared__ float tile[32][33];
  int tn = blockIdx.x * 32;
  int tk = blockIdx.y * 32;
  int tx = threadIdx.x & 31;
  int ty = threadIdx.x >> 5;  // 0..7
  #pragma unroll
  for (int i = 0; i < 4; i++) {
    int k = tk + ty + i * 8;
    tile[ty + i * 8][tx] = W[(size_t)k * N + tn + tx];
  }
  __syncthreads();
  #pragma unroll
  for (int i = 0; i < 4; i++) {
    int n = tn + ty + i * 8;
    Wt[(size_t)n * K + tk + tx] = f2bf(tile[tx][ty + i * 8]);
  }
}

// ---------------- RoPE in place on [B][S][nheads][128] bf16 ----------------
__global__ void rope_kernel(unsigned short* __restrict__ Qb, int nheads) {
  int idx = blockIdx.x * blockDim.x + threadIdx.x;
  int d = idx & 63;
  int hr = idx >> 6;                 // (b*SEQ + s)*nheads + h
  int spos = (hr / nheads) % SEQ;
  size_t base = (size_t)hr * HD;
  float inv = exp2f((float)d * -0.2076205059304601f);  // 10000^(-d/64)
  float ang = (float)spos * inv;
  float sn, cs;
  sincosf(ang, &sn, &cs);
  float q1 = bf2f(Qb[base + d]);
  float q2 = bf2f(Qb[base + d + 64]);
  Qb[base + d]      = f2bf(q1 * cs - q2 * sn);
  Qb[base + d + 64] = f2bf(q2 * cs + q1 * sn);
}

// ================= fused QKV GEMM: xb[4096][2048] x Wqkvt[3072][2048]^T ================
// double-buffered LDS (distinct static arrays for clean alias analysis),
// loads for k+32 in flight during compute of k. Epilogue splits Q/K/V (V transposed).
__global__ __launch_bounds__(256) void gemm_qkv(
    const unsigned short* __restrict__ A,
    const unsigned short* __restrict__ Bt,
    unsigned short* __restrict__ Qb,
    unsigned short* __restrict__ Kb,
    unsigned short* __restrict__ Vt) {
  __shared__ unsigned short As0[128 * 32], Bs0[128 * 32];
  __shared__ unsigned short As1[128 * 32], Bs1[128 * 32];
  const int K = HIDDEN;
  int bm = blockIdx.y * 128, bn = blockIdx.x * 128;
  int tid = threadIdx.x, w = tid >> 6, lane = tid & 63;
  int wm = (w >> 1) * 64, wn = (w & 1) * 64;
  int m16 = lane & 15, quad = lane >> 4;
  int lrow = lane >> 2, lch = lane & 3;
  const unsigned short* Ag = A + (size_t)(bm + w * 32 + lrow) * K + lch * 8;
  const unsigned short* Bg = Bt + (size_t)(bn + w * 32 + lrow) * K + lch * 8;
  int woff = w * 1024;

  float4v acc[4][4];
  #pragma unroll
  for (int i = 0; i < 4; i++)
    #pragma unroll
    for (int j = 0; j < 4; j++) acc[i][j] = (float4v)0.0f;

  auto stage = [&](int k0, unsigned short* Asl, unsigned short* Bsl) {
    #pragma unroll
    for (int i = 0; i < 2; i++) {
      async16(Ag + (size_t)i * 16 * K + k0, Asl + woff + i * 512);
      async16(Bg + (size_t)i * 16 * K + k0, Bsl + woff + i * 512);
    }
  };
  auto compute = [&](const unsigned short* As, const unsigned short* Bs) {
    short8 af[4], bfr[4];
    #pragma unroll
    for (int i = 0; i < 4; i++)
      af[i] = *(const short8*)(&As[(wm + i * 16 + m16) * 32 + quad * 8]);
    #pragma unroll
    for (int j = 0; j < 4; j++)
      bfr[j] = *(const short8*)(&Bs[(wn + j * 16 + m16) * 32 + quad * 8]);
    #pragma unroll
    for (int i = 0; i < 4; i++)
      #pragma unroll
      for (int j = 0; j < 4; j++)
        acc[i][j] = __builtin_amdgcn_mfma_f32_16x16x32_bf16(af[i], bfr[j], acc[i][j], 0, 0, 0);
  };

  stage(0, As0, Bs0);
  for (int k0 = 0; k0 < K; k0 += 64) {
    __syncthreads();                       // drains buf0 loads (overlapped w/ prev compute)
    if (k0 + 32 < K) stage(k0 + 32, As1, Bs1);
    compute(As0, Bs0);
    __syncthreads();                       // drains buf1 loads (overlapped w/ compute above)
    if (k0 + 64 < K) stage(k0 + 64, As0, Bs0);
    compute(As1, Bs1);
  }

  // epilogue: blockIdx.x<16 -> Q rows; 16..19 -> K rows; 20..23 -> V transposed
  if (blockIdx.x < 16) {
    #pragma unroll
    for (int i = 0; i < 4; i++)
      #pragma unroll
      for (int j = 0; j < 4; j++)
        #pragma unroll
        for (int r = 0; r < 4; r++) {
          int row = bm + wm + i * 16 + quad * 4 + r;
          int col = bn + wn + j * 16 + m16;
          Qb[(size_t)row * NQ + col] = f2bf(acc[i][j][r]);
        }
  } else if (blockIdx.x < 20) {
    #pragma unroll
    for (int i = 0; i < 4; i++)
      #pragma unroll
      for (int j = 0; j < 4; j++)
        #pragma unroll
        for (int r = 0; r < 4; r++) {
          int row = bm + wm + i * 16 + quad * 4 + r;
          int col = bn - 2048 + wn + j * 16 + m16;
          Kb[(size_t)row * NKVD + col] = f2bf(acc[i][j][r]);
        }
  } else {
    #pragma unroll
    for (int i = 0; i < 4; i++)
      #pragma unroll
      for (int j = 0; j < 4; j++) {
        int f = bn - 2560 + wn + j * 16 + m16;
        int row0 = bm + wm + i * 16 + quad * 4;
        uint2 u;
        u.x = ((unsigned)f2bf(acc[i][j][1]) << 16) | f2bf(acc[i][j][0]);
        u.y = ((unsigned)f2bf(acc[i][j][3]) << 16) | f2bf(acc[i][j][2]);
        *(uint2*)(Vt + (size_t)f * MTOT + row0) = u;
      }
  }
}

// ================= O-projection GEMM (same dbuf core, fp32 out) =================
__global__ __launch_bounds__(256) void gemm_o(
    const unsigned short* __restrict__ A,
    const unsigned short* __restrict__ Bt,
    float* __restrict__ C, int M, int N, int K) {
  __shared__ unsigned short As0[128 * 32], Bs0[128 * 32];
  __shared__ unsigned short As1[128 * 32], Bs1[128 * 32];
  int bm = blockIdx.y * 128, bn = blockIdx.x * 128;
  int tid = threadIdx.x, w = tid >> 6, lane = tid & 63;
  int wm = (w >> 1) * 64, wn = (w & 1) * 64;
  int m16 = lane & 15, quad = lane >> 4;
  int lrow = lane >> 2, lch = lane & 3;
  const unsigned short* Ag = A + (size_t)(bm + w * 32 + lrow) * K + lch * 8;
  const unsigned short* Bg = Bt + (size_t)(bn + w * 32 + lrow) * K + lch * 8;
  int woff = w * 1024;

  float4v acc[4][4];
  #pragma unroll
  for (int i = 0; i < 4; i++)
    #pragma unroll
    for (int j = 0; j < 4; j++) acc[i][j] = (float4v)0.0f;

  auto stage = [&](int k0, unsigned short* Asl, unsigned short* Bsl) {
    #pragma unroll
    for (int i = 0; i < 2; i++) {
      async16(Ag + (size_t)i * 16 * K + k0, Asl + woff + i * 512);
      async16(Bg + (size_t)i * 16 * K + k0, Bsl + woff + i * 512);
    }
  };
  auto compute = [&](const unsigned short* As, const unsigned short* Bs) {
    short8 af[4], bfr[4];
    #pragma unroll
    for (int i = 0; i < 4; i++)
      af[i] = *(const short8*)(&As[(wm + i * 16 + m16) * 32 + quad * 8]);
    #pragma unroll
    for (int j = 0; j < 4; j++)
      bfr[j] = *(const short8*)(&Bs[(wn + j * 16 + m16) * 32 + quad * 8]);
    #pragma unroll
    for (int i = 0; i < 4; i++)
      #pragma unroll
      for (int j = 0; j < 4; j++)
        acc[i][j] = __builtin_amdgcn_mfma_f32_16x16x32_bf16(af[i], bfr[j], acc[i][j], 0, 0, 0);
  };

  stage(0, As0, Bs0);
  for (int k0 = 0; k0 < K; k0 += 64) {
    __syncthreads();
    if (k0 + 32 < K) stage(k0 + 32, As1, Bs1);
    compute(As0, Bs0);
    __syncthreads();
    if (k0 + 64 < K) stage(k0 + 64, As0, Bs0);
    compute(As1, Bs1);
  }

  #pragma unroll
  for (int i = 0; i < 4; i++)
    #pragma unroll
    for (int j = 0; j < 4; j++)
      #pragma unroll
      for (int r = 0; r < 4; r++) {
        int row = bm + wm + i * 16 + quad * 4 + r;
        int col = bn + wn + j * 16 + m16;
        C[(size_t)row * N + col] = acc[i][j][r];
      }
}

// ---------------- Flash attention (causal, GQA), S^T formulation ----------------
// Double-buffered K staging; V-load latency hidden under S+softmax; K(kt+1) issued
// after S-MFMA so the mid-barrier drain is covered by softmax. LDS = exactly 64 KB.
#define FLASH_TILE(CUR, NXT)                                                  \
  {                                                                           \
    const int ktb = kt * 64;                                                  \
    __syncthreads(); /* TOP: nothing in flight; protects Vs reuse */          \
    {                                                                         \
      const unsigned short* Vg = Vt + vgrow * (size_t)MTOT                    \
                                    + (size_t)b * SEQ + ktb + kcv * 32 + lch * 8; \
      unsigned short* Vl = Vs + kcv * 4096 + ipv * 512;                       \
      _Pragma("unroll")                                                       \
      for (int i = 0; i < 4; i++) async16(Vg + (size_t)i * 16 * MTOT, Vl + i * 512); \
    }                                                                         \
    const bool act = (ktb <= wqmax);                                          \
    float4v sacc[2][4];                                                       \
    if (act) {                                                                \
      _Pragma("unroll") for (int qs = 0; qs < 2; qs++)                        \
        _Pragma("unroll") for (int s4 = 0; s4 < 4; s4++) sacc[qs][s4] = (float4v)0.0f; \
      _Pragma("unroll")                                                       \
      for (int s4 = 0; s4 < 4; s4++)                                          \
        _Pragma("unroll")                                                     \
        for (int c = 0; c < 4; c++) {                                         \
          short8 kf = *(const short8*)(&CUR[c * 2048 + (s4 * 16 + m16) * 32 + quad * 8]); \
          sacc[0][s4] = __builtin_amdgcn_mfma_f32_16x16x32_bf16(kf, qf[0][c], sacc[0][s4], 0, 0, 0); \
          sacc[1][s4] = __builtin_amdgcn_mfma_f32_16x16x32_bf16(kf, qf[1][c], sacc[1][s4], 0, 0, 0); \
        }                                                                     \
    }                                                                         \
    if (kt < H) {                                                             \
      const unsigned short* Kg = Kp + (((size_t)b * SEQ + (kt + 1) * 64 + lrow) * NKV + kvh) * HD + w * 32 + lch * 8; \
      unsigned short* Kl = NXT + w * 2048;                                    \
      _Pragma("unroll")                                                       \
      for (int i = 0; i < 4; i++) async16(Kg + (size_t)i * 16 * NKV * HD, Kl + i * 512); \
    }                                                                         \
    if (act) {                                                                \
      _Pragma("unroll")                                                       \
      for (int qs = 0; qs < 2; qs++) {                                        \
        const int qabs = wqbase + qs * 16 + m16;                              \
        const bool diag = (ktb + 63) > (wqbase + qs * 16);                    \
        float sv[4][4]; float mloc = -1e30f;                                  \
        if (diag) {                                                           \
          _Pragma("unroll") for (int s4 = 0; s4 < 4; s4++)                    \
            _Pragma("unroll") for (int r = 0; r < 4; r++) {                   \
              int kabs = ktb + s4 * 16 + quad * 4 + r;                        \
              float t = sacc[qs][s4][r];                                      \
              sv[s4][r] = (kabs > qabs) ? -1e30f : t;                         \
              mloc = fmaxf(mloc, sv[s4][r]); }                                \
        } else {                                                              \
          _Pragma("unroll") for (int s4 = 0; s4 < 4; s4++)                    \
            _Pragma("unroll") for (int r = 0; r < 4; r++) {                   \
              sv[s4][r] = sacc[qs][s4][r]; mloc = fmaxf(mloc, sv[s4][r]); }   \
        }                                                                     \
        mloc *= C1;                                                           \
        mloc = fmaxf(mloc, __shfl_xor(mloc, 16, 64));                         \
        mloc = fmaxf(mloc, __shfl_xor(mloc, 32, 64));                         \
        const float mnewS = fmaxf(miS[qs], mloc);                             \
        float pr[4][4]; float rs = 0.0f;                                      \
        _Pragma("unroll") for (int s4 = 0; s4 < 4; s4++)                      \
          _Pragma("unroll") for (int r = 0; r < 4; r++) {                     \
            float p = EXP2F(__builtin_fmaf(sv[s4][r], C1, -mnewS));           \
            pr[s4][r] = p; rs += p; }                                         \
        rs += __shfl_xor(rs, 16, 64);                                         \
        rs += __shfl_xor(rs, 32, 64);                                         \
        const float alpha = EXP2F(miS[qs] - mnewS);                           \
        li[qs] = li[qs] * alpha + rs; miS[qs] = mnewS;                        \
        _Pragma("unroll") for (int ds = 0; ds < 8; ds++) oacc[ds][qs] *= alpha; \
        const int prow = qlocal0 + qs * 16 + m16;                             \
        const int psw = prow * 32; const int rx = prow & 7;                   \
        _Pragma("unroll") for (int s4 = 0; s4 < 4; s4++) {                    \
          uint2 u;                                                            \
          u.x = (__float_as_uint(pr[s4][1]) & 0xffff0000u) | (__float_as_uint(pr[s4][0]) >> 16); \
          u.y = (__float_as_uint(pr[s4][3]) & 0xffff0000u) | (__float_as_uint(pr[s4][2]) >> 16); \
          int chunkW = s4 * 2 + (quad >> 1);                                  \
          *(uint2*)(&Ps[psw + ((chunkW ^ rx) << 2) + (quad & 1) * 2]) = u;    \
        }                                                                     \
      }                                                                       \
    }                                                                         \
    __syncthreads(); /* MID: drains V(kt)+K(kt+1), covered by S+softmax */    \
    if (act) {                                                                \
      const int r0 = qlocal0 + m16, r1 = qlocal0 + 16 + m16;                  \
      _Pragma("unroll")                                                       \
      for (int kc = 0; kc < 2; kc++) {                                        \
        short8 pf0 = *(const short8*)(&Ps[r0 * 32 + (((kc * 4 + quad) ^ (r0 & 7)) << 2)]); \
        short8 pf1 = *(const short8*)(&Ps[r1 * 32 + (((kc * 4 + quad) ^ (r1 & 7)) << 2)]); \
        _Pragma("unroll")                                                     \
        for (int ds = 0; ds < 8; ds++) {                                      \
          short8 vf = *(const short8*)(&Vs[kc * 4096 + (ds * 16 + m16) * 32 + quad * 8]); \
          oacc[ds][0] = __builtin_amdgcn_mfma_f32_16x16x32_bf16(vf, pf0, oacc[ds][0], 0, 0, 0); \
          oacc[ds][1] = __builtin_amdgcn_mfma_f32_16x16x32_bf16(vf, pf1, oacc[ds][1], 0, 0, 0); \
        }                                                                     \
      }                                                                       \
    }                                                                         \
  }

__global__ __launch_bounds__(256, 2) void flash_attn(
    const unsigned short* __restrict__ Q,
    const unsigned short* __restrict__ Kp,
    const unsigned short* __restrict__ Vt,
    unsigned short* __restrict__ O) {
  __shared__ unsigned short Ks0[4 * 64 * 32];  // 16 KB  [dchunk][key][32d]
  __shared__ unsigned short Ks1[4 * 64 * 32];  // 16 KB
  __shared__ unsigned short Vs[2 * 128 * 32];  // 16 KB  [kchunk][d][32seq]
  __shared__ unsigned int   Ps[128 * 32];      // 16 KB  XOR-swizzled P[q][k/2]

  int bx = blockIdx.x;            // 0..15
  int h  = blockIdx.y;
  int b  = blockIdx.z;
  int kvh = h >> 2;
  int H = 31 - bx, L = bx;
  int tid = threadIdx.x;
  int w = tid >> 6, lane = tid & 63;
  int m16 = lane & 15, quad = lane >> 4;
  int lrow = lane >> 2, lch = lane & 3;

  int wqbase = (w < 2) ? (H * 64 + w * 32) : (L * 64 + (w - 2) * 32);
  int wqmax = wqbase + 31;
  int qlocal0 = w * 32;
  const int kcv = w >> 1, ipv = (w & 1) * 4;
  const size_t vgrow = (size_t)kvh * HD + ipv * 16 + lrow;

  short8 qf[2][4];
  #pragma unroll
  for (int qs = 0; qs < 2; qs++) {
    size_t qbase = (((size_t)b * SEQ + wqbase + qs * 16 + m16) * NHEADS + h) * HD;
    #pragma unroll
    for (int c = 0; c < 4; c++)
      qf[qs][c] = *(const short8*)(Q + qbase + c * 32 + quad * 8);
  }

  float4v oacc[8][2];
  #pragma unroll
  for (int ds = 0; ds < 8; ds++) { oacc[ds][0] = (float4v)0.0f; oacc[ds][1] = (float4v)0.0f; }
  float miS[2] = {-1e30f, -1e30f}, li[2] = {0.0f, 0.0f};

  // prologue: stage K(0) into Ks0 (drained at first TOP barrier)
  {
    const unsigned short* Kg = Kp + (((size_t)b * SEQ + lrow) * NKV + kvh) * HD + w * 32 + lch * 8;
    unsigned short* Kl = Ks0 + w * 2048;
    #pragma unroll
    for (int i = 0; i < 4; i++) async16(Kg + (size_t)i * 16 * NKV * HD, Kl + i * 512);
  }

  int kt = 0;
  for (;;) {
    FLASH_TILE(Ks0, Ks1)
    if (++kt > H) break;
    FLASH_TILE(Ks1, Ks0)
    if (++kt > H) break;
  }

  #pragma unroll
  for (int qs = 0; qs < 2; qs++) {
    float inv = 1.0f / li[qs];
    int qabs = wqbase + qs * 16 + m16;
    size_t obase = (((size_t)b * SEQ + qabs) * NHEADS + h) * HD + quad * 4;
    #pragma unroll
    for (int ds = 0; ds < 8; ds++) {
      float v0 = oacc[ds][qs][0] * inv;
      float v1 = oacc[ds][qs][1] * inv;
      float v2 = oacc[ds][qs][2] * inv;
      float v3 = oacc[ds][qs][3] * inv;
      uint2 u;
      u.x = ((unsigned)f2bf(v1) << 16) | f2bf(v0);
      u.y = ((unsigned)f2bf(v3) << 16) | f2bf(v2);
      *(uint2*)(O + obase + ds * 16) = u;
    }
  }
}

extern "C" void kernel_launch(void* const* d_in, const int* in_sizes, int n_in,
                              void* d_out, int out_size, void* d_ws, size_t ws_size,
                              hipStream_t stream) {
  const float* x  = (const float*)d_in[0];
  const float* Wq = (const float*)d_in[1];
  const float* Wk = (const float*)d_in[2];
  const float* Wv = (const float*)d_in[3];
  const float* Wo = (const float*)d_in[4];
  float* out = (float*)d_out;

  unsigned short* ws = (unsigned short*)d_ws;
  unsigned short* xb  = ws;                              // [4096][2048]
  unsigned short* Wqt = xb  + (size_t)MTOT * HIDDEN;     // [2048][2048] (Wqt/Wkt/Wvt contiguous = Wqkvt[3072][2048])
  unsigned short* Wkt = Wqt + (size_t)NQ * HIDDEN;       // [512][2048]
  unsigned short* Wvt = Wkt + (size_t)NKVD * HIDDEN;     // [512][2048]
  unsigned short* Wot = Wvt + (size_t)NKVD * HIDDEN;     // [2048][2048]
  unsigned short* Qb  = Wot + (size_t)NQ * HIDDEN;       // [4096][2048]
  unsigned short* Kb  = Qb  + (size_t)MTOT * NQ;         // [4096][512]
  unsigned short* Vtb = Kb  + (size_t)MTOT * NKVD;       // [512][4096]  (V^T)
  unsigned short* Ab  = Vtb + (size_t)MTOT * NKVD;       // [4096][2048]

  cast_f32_bf16<<<(MTOT * HIDDEN / 4 + 255) / 256, 256, 0, stream>>>(x, xb, MTOT * HIDDEN);
  transpose_cast<<<dim3(NQ / 32, HIDDEN / 32), 256, 0, stream>>>(Wq, Wqt, HIDDEN, NQ);
  transpose_cast<<<dim3(NKVD / 32, HIDDEN / 32), 256, 0, stream>>>(Wk, Wkt, HIDDEN, NKVD);
  transpose_cast<<<dim3(NKVD / 32, HIDDEN / 32), 256, 0, stream>>>(Wv, Wvt, HIDDEN, NKVD);
  transpose_cast<<<dim3(NQ / 32, HIDDEN / 32), 256, 0, stream>>>(Wo, Wot, NQ, HIDDEN);

  // fused QKV projection (V written transposed)
  gemm_qkv<<<dim3(NQKV / 128, MTOT / 128), 256, 0, stream>>>(xb, Wqt, Qb, Kb, Vtb);

  rope_kernel<<<(BATCH * SEQ * NHEADS * 64) / 256, 256, 0, stream>>>(Qb, NHEADS);
  rope_kernel<<<(BATCH * SEQ * NKV * 64) / 256, 256, 0, stream>>>(Kb, NKV);

  flash_attn<<<dim3(16, NHEADS, BATCH), 256, 0, stream>>>(Qb, Kb, Vtb, Ab);

  gemm_o<<<dim3(HIDDEN / 128, MTOT / 128), 256, 0, stream>>>(Ab, Wot, out, MTOT, HIDDEN, NQ);
}